// Round 5
// baseline (252.371 us; speedup 1.0000x reference)
//
#include <hip/hip_runtime.h>
#include <math.h>

#define NROWS 65536
#define DDIM  64
#define KCB   1024
#define TILE  16            // codes staged per tile
#define NTILE (256 / TILE)  // 16 tiles per wave slice

// ---------------------------------------------------------------------------
// Kernel 1: C2[j] = ||W_j||^2 via numpy pairwise-sum emulation (n=64: 8 accs).
// ---------------------------------------------------------------------------
__global__ void vq_c2_kernel(const float* __restrict__ W, float* __restrict__ C2) {
    int j = blockIdx.x * blockDim.x + threadIdx.x;
    if (j >= KCB) return;
    const float* w = W + (size_t)j * DDIM;
    float r[8];
#pragma unroll
    for (int m = 0; m < 8; ++m) r[m] = __fmul_rn(w[m], w[m]);
#pragma unroll
    for (int i = 8; i < 64; i += 8) {
#pragma unroll
        for (int m = 0; m < 8; ++m)
            r[m] = __fadd_rn(r[m], __fmul_rn(w[i + m], w[i + m]));
    }
    float res = __fadd_rn(
        __fadd_rn(__fadd_rn(r[0], r[1]), __fadd_rn(r[2], r[3])),
        __fadd_rn(__fadd_rn(r[4], r[5]), __fadd_rn(r[6], r[7])));
    C2[j] = res;
}

// ---------------------------------------------------------------------------
// Kernel 2: main argmin. Round-0 wave decomposition (4 waves x 64 rows,
// wave s scans codes [s*256, s*256+256)) — but W is delivered through LDS.
//
// WHY: rounds 0/1/2/4 all compiled to the same binary (VGPR=40 SGPR=96,
// 168us): every wave-uniform W access gets scalarized to s_load; at the
// 102-SGPR cap a 64-float row can't be double-buffered, so each code pays
// s_load x8 -> lgkmcnt(0) through a thrashing 16KB K$ (~230cyc stall vs
// 128cyc of FMA). Real VALU busy is ~61us (VALUBusy counter uses a SIMD-16
// era formula, ~2x inflated); the rest is scalar-fetch stall.
//
// LDS reads cannot be scalarized. Pipeline, per wave (no cross-wave sync):
//   regs stg[4] <- coalesced float4 loads of tile t+1 (issued ~2500cyc early)
//   ds_write stg -> per-wave 4KB buffer (compiler inserts vmcnt waits)
//   consume: 16 codes, each = 16 uniform ds_read_b128 (broadcast,
//            conflict-free, L2-latency-free) + the exact 64-FMA chain.
// DS ops are in-order per wave and the compiler tracks the LDS aliasing, so
// no manual waitcnt/barriers are needed.
//
// Math byte-identical to the 222us anchor: CL = sequential fp32 FMA chain
// k=0..63, dist = (L2 - 2*CL) + C2, L2 pairwise-8. Strict-< ascending-j
// tie-break (tiles ascend, codes within tile ascend, waves combine ascend).
// ---------------------------------------------------------------------------
__global__ void __launch_bounds__(256, 4)
vq_main_kernel(const float* __restrict__ x, const float* __restrict__ W,
               const float* __restrict__ C2, int* __restrict__ cls_i,
               float* __restrict__ cls_f) {
    __shared__ float4 sW4[4][TILE * DDIM / 4];  // per-wave 4KB tile, 16KB total
    __shared__ float  s_bd[4][64];
    __shared__ int    s_bi[4][64];

    const int lane = threadIdx.x & 63;
    const int s    = __builtin_amdgcn_readfirstlane(threadIdx.x >> 6);
    const int row  = blockIdx.x * 64 + lane;

    // Load this row of x into registers (16 x float4).
    const float* xr = x + (size_t)row * DDIM;
    float xv[64];
#pragma unroll
    for (int k = 0; k < 64; k += 4) {
        float4 v = *(const float4*)(xr + k);
        xv[k] = v.x; xv[k + 1] = v.y; xv[k + 2] = v.z; xv[k + 3] = v.w;
    }

    // L2 = numpy pairwise sum of x*x (n=64).
    float r[8];
#pragma unroll
    for (int m = 0; m < 8; ++m) r[m] = __fmul_rn(xv[m], xv[m]);
#pragma unroll
    for (int i = 8; i < 64; i += 8) {
#pragma unroll
        for (int m = 0; m < 8; ++m)
            r[m] = __fadd_rn(r[m], __fmul_rn(xv[i + m], xv[i + m]));
    }
    const float L2 = __fadd_rn(
        __fadd_rn(__fadd_rn(r[0], r[1]), __fadd_rn(r[2], r[3])),
        __fadd_rn(__fadd_rn(r[4], r[5]), __fadd_rn(r[6], r[7])));

    float best = INFINITY;
    int   bidx = 0;
    const int j0 = s * 256;
    // Wave slice of W in float4 units; tile t = float4 [t*256, t*256+256).
    const float4* wg = (const float4*)(W + (size_t)j0 * DDIM);

    // Prologue: tile 0 into staging regs (4 coalesced float4 per lane).
    float4 stg[4];
#pragma unroll
    for (int q = 0; q < 4; ++q) stg[q] = wg[q * 64 + lane];

#pragma unroll 1
    for (int t = 0; t < NTILE; ++t) {
        // Stage regs -> this wave's LDS buffer (linear: float4 idx q*64+lane
        // == global float4 offset within the tile, so lds float f maps to
        // code f>>6, k = f&63).
        float4* buf = &sW4[s][0];
#pragma unroll
        for (int q = 0; q < 4; ++q) buf[q * 64 + lane] = stg[q];

        // Issue next tile's loads now; they land while we consume this tile.
        if (t < NTILE - 1) {
            const float4* wgn = wg + (t + 1) * 256;
#pragma unroll
            for (int q = 0; q < 4; ++q) stg[q] = wgn[q * 64 + lane];
        }

        // Consume 16 codes from LDS (uniform broadcast ds_read_b128).
#pragma unroll 1
        for (int jj = 0; jj < TILE; ++jj) {
            const float4* wl = buf + jj * 16;  // wave-uniform address
            float acc = 0.0f;
#pragma unroll
            for (int c = 0; c < 16; ++c) {
                const float4 wv = wl[c];
                acc = __builtin_fmaf(xv[4 * c + 0], wv.x, acc);
                acc = __builtin_fmaf(xv[4 * c + 1], wv.y, acc);
                acc = __builtin_fmaf(xv[4 * c + 2], wv.z, acc);
                acc = __builtin_fmaf(xv[4 * c + 3], wv.w, acc);
            }
            const int j = j0 + t * TILE + jj;
            const float dist =
                __fadd_rn(__fsub_rn(L2, __fmul_rn(2.0f, acc)), C2[j]);
            if (dist < best) { best = dist; bidx = j; }  // strict <: lowest j
        }
    }

    s_bd[s][lane] = best;
    s_bi[s][lane] = bidx;
    __syncthreads();

    if (s == 0) {
        float b  = s_bd[0][lane];
        int   bi = s_bi[0][lane];
#pragma unroll
        for (int t = 1; t < 4; ++t) {
            const float d = s_bd[t][lane];
            if (d < b) { b = d; bi = s_bi[t][lane]; }  // ascending j-ranges
        }
        cls_i[row] = bi;
        cls_f[row] = (float)bi;  // harness reads indices as fp32
    }
}

// ---------------------------------------------------------------------------
// Kernel 3: gather quantized = W[closest]. 16 threads/row, float4 each.
// ---------------------------------------------------------------------------
__global__ void vq_gather_kernel(const float* __restrict__ W,
                                 const int* __restrict__ cls,
                                 float* __restrict__ outq) {
    const int t = blockIdx.x * blockDim.x + threadIdx.x;
    const int i = t >> 4;
    const int q = t & 15;
    const int j = cls[i];
    const float4 v = *(const float4*)(W + (size_t)j * DDIM + q * 4);
    *(float4*)(outq + (size_t)i * DDIM + q * 4) = v;
}

extern "C" void kernel_launch(void* const* d_in, const int* in_sizes, int n_in,
                              void* d_out, int out_size, void* d_ws, size_t ws_size,
                              hipStream_t stream) {
    const float* x = (const float*)d_in[0];
    const float* W = (const float*)d_in[1];

    float* outq = (float*)d_out;                        // N*D quantized
    float* outi = (float*)d_out + (size_t)NROWS * DDIM; // N indices as float

    float* C2  = (float*)d_ws;                          // 4 KB
    int*   cls = (int*)((char*)d_ws + 4096);            // 256 KB

    hipLaunchKernelGGL(vq_c2_kernel, dim3(KCB / 256), dim3(256), 0, stream, W, C2);
    hipLaunchKernelGGL(vq_main_kernel, dim3(NROWS / 64), dim3(256), 0, stream,
                       x, W, C2, cls, outi);
    hipLaunchKernelGGL(vq_gather_kernel, dim3((NROWS * 16) / 256), dim3(256), 0,
                       stream, W, cls, outq);
}